// Round 2
// baseline (345.625 us; speedup 1.0000x reference)
//
#include <hip/hip_runtime.h>

#define N_NODES 50000
#define N_EDGES 800000
#define IN_F    512
#define NH      4
#define DH      64
#define HD      256   // NH*DH
#define NEG     0.2f
#define NB      ((N_NODES + 255) / 256)   // 196 scan blocks

typedef __attribute__((ext_vector_type(8))) short bf16x8;
typedef __attribute__((ext_vector_type(4))) float f32x4;

__device__ __forceinline__ unsigned short f2bf(float x) {
    unsigned u = __float_as_uint(x);
    unsigned r = (u + 0x7FFFu + ((u >> 16) & 1u)) >> 16;  // RNE
    return (unsigned short)r;
}
__device__ __forceinline__ float bf2f(unsigned short b) {
    return __uint_as_float((unsigned)b << 16);
}

// ---------------- setup: zero counts + W -> WtbT (K-tiled + XOR-swizzled) ----
// WtbT layout: tile t = k/64 (32KB each, contiguous), within tile the 16B
// granule for (col n, k-granule g) sits at linear granule n*8 + (g ^ (n&7)).
// This is exactly the linear order global_load_lds stages, so the LDS copy is
// a straight memcpy and the ds_read applies the same XOR -> bank-uniform.
__global__ __launch_bounds__(256) void setup_kernel(const float* __restrict__ W,
                                                    unsigned short* __restrict__ WtbT,
                                                    int* __restrict__ counts) {
    int b = blockIdx.x;
    if (b < NB) {
        int i = b * 256 + threadIdx.x;
        if (i < N_NODES) counts[i] = 0;
    } else {
        int i = (b - NB) * 256 + threadIdx.x;   // over 512*256
        if (i < IN_F * HD) {
            int k = i >> 8;        // 0..511
            int n = i & 255;       // 0..255
            int t  = k >> 6;       // k-tile
            int kk = k & 63;
            int g  = kk >> 3;      // 16B granule within row
            int w8 = kk & 7;
            int p  = n * 8 + (g ^ (n & 7));     // swizzled granule
            WtbT[(size_t)t * 16384 + p * 8 + w8] = f2bf(W[i]);
        }
    }
}

// ---------------- per-dst edge counts ----------------
__global__ __launch_bounds__(256) void count_kernel(const int* __restrict__ dst,
                                                    int* __restrict__ counts) {
    int e = blockIdx.x * blockDim.x + threadIdx.x;
    if (e < N_EDGES) atomicAdd(&counts[dst[e]], 1);
}

// ---------------- bf16 MFMA GEMM: ftb = bf16(feat @ W), el/er fused -----------
// 64x256 tile, BK=64, 4 waves (wave == head == 64-col block), acc[4][4].
// B staged with global_load_lds width-16 into double-buffered LINEAR LDS
// (source pre-swizzled in WtbT, reads XOR-swizzled -> conflict-optimal).
// A reg-staged (fp32->bf16 convert) into padded LDS. Next tile's A regs and
// B DMA fly during the whole compute phase; the barrier2 drain lands after.
#define LDPA 72   // padded LDS row stride in shorts
__global__ __launch_bounds__(256) void gemm_kernel(const float* __restrict__ A,
                                                   const unsigned short* __restrict__ WtbT,
                                                   const float* __restrict__ attn_l,
                                                   const float* __restrict__ attn_r,
                                                   unsigned short* __restrict__ Cb,
                                                   float* __restrict__ el,
                                                   float* __restrict__ er) {
    __shared__ short A_s[64][LDPA];       // 9.2 KB
    __shared__ short B_s[2][256 * 64];    // 64 KB (double buffer, linear)

    const int tid  = threadIdx.x;
    const int lane = tid & 63;
    const int w    = tid >> 6;      // wave id == head id == col block
    const int lm   = lane & 15;
    const int quad = lane >> 4;
    const int row0 = blockIdx.x * 64;

    // A staging: 64x64 fp32, 2 rows of 8 floats per thread
    const int srow = tid >> 3;          // 0..31
    const int sc8  = (tid & 7) * 8;

    f32x4 acc[4][4] = {};
    float4 pa[4];

#define STAGE_B(BUF, T)                                                         \
    {                                                                           \
        const char* gsrc = (const char*)WtbT + (size_t)(T) * 32768 + tid * 16;  \
        char* ldst = (char*)&B_s[BUF][0] + tid * 16;                            \
        _Pragma("unroll")                                                       \
        for (int r = 0; r < 8; r++)                                             \
            __builtin_amdgcn_global_load_lds(                                   \
                (const __attribute__((address_space(1))) unsigned int*)(gsrc + r * 4096), \
                (__attribute__((address_space(3))) unsigned int*)(ldst + r * 4096),       \
                16, 0, 0);                                                      \
    }

#define LOAD_A(KT)                                                             \
    {                                                                          \
        int g0 = row0 + srow;                                                  \
        if (g0 < N_NODES) {                                                    \
            const float* ap = A + (size_t)g0 * IN_F + (KT) + sc8;              \
            pa[0] = *(const float4*)ap; pa[1] = *(const float4*)(ap + 4);      \
        } else { pa[0] = pa[1] = make_float4(0.f, 0.f, 0.f, 0.f); }            \
        int g1 = row0 + 32 + srow;                                             \
        if (g1 < N_NODES) {                                                    \
            const float* ap = A + (size_t)g1 * IN_F + (KT) + sc8;              \
            pa[2] = *(const float4*)ap; pa[3] = *(const float4*)(ap + 4);      \
        } else { pa[2] = pa[3] = make_float4(0.f, 0.f, 0.f, 0.f); }            \
    }

    STAGE_B(0, 0);
    LOAD_A(0);

    int buf = 0;
    for (int t = 0; t < 8; t++) {
        // convert + store current A tile to LDS (vmcnt wait lands here)
        {
            bf16x8 s;
            s[0] = (short)f2bf(pa[0].x); s[1] = (short)f2bf(pa[0].y);
            s[2] = (short)f2bf(pa[0].z); s[3] = (short)f2bf(pa[0].w);
            s[4] = (short)f2bf(pa[1].x); s[5] = (short)f2bf(pa[1].y);
            s[6] = (short)f2bf(pa[1].z); s[7] = (short)f2bf(pa[1].w);
            *(bf16x8*)(&A_s[srow][sc8]) = s;
            s[0] = (short)f2bf(pa[2].x); s[1] = (short)f2bf(pa[2].y);
            s[2] = (short)f2bf(pa[2].z); s[3] = (short)f2bf(pa[2].w);
            s[4] = (short)f2bf(pa[3].x); s[5] = (short)f2bf(pa[3].y);
            s[6] = (short)f2bf(pa[3].z); s[7] = (short)f2bf(pa[3].w);
            *(bf16x8*)(&A_s[32 + srow][sc8]) = s;
        }
        __syncthreads();   // A_s visible; B_s[buf] DMA complete (drained here/at prev barrier)

        // issue next tile's B DMA + A loads (fly during compute below)
        if (t + 1 < 8) { STAGE_B(buf ^ 1, t + 1); LOAD_A((t + 1) * 64); }

        // compute current tile
#pragma unroll
        for (int kk = 0; kk < 64; kk += 32) {
            bf16x8 af[4], bfr[4];
#pragma unroll
            for (int i = 0; i < 4; i++)
                af[i] = *(const bf16x8*)(&A_s[i * 16 + lm][kk + quad * 8]);
#pragma unroll
            for (int j = 0; j < 4; j++) {
                int n  = w * 64 + j * 16 + lm;
                int g  = (kk >> 3) + quad;
                int gs = g ^ (lm & 7);
                bfr[j] = *(const bf16x8*)(&B_s[buf][(n * 8 + gs) * 8]);
            }
#pragma unroll
            for (int i = 0; i < 4; i++)
#pragma unroll
                for (int j = 0; j < 4; j++)
                    acc[i][j] = __builtin_amdgcn_mfma_f32_16x16x32_bf16(
                        af[i], bfr[j], acc[i][j], 0, 0, 0);
        }
        if (t < 7) __syncthreads();   // protect LDS before next iteration's stores
        buf ^= 1;
    }
#undef LOAD_A
#undef STAGE_B

    // C/D layout: col = lane&15, row = quad*4 + reg; store bf16
#pragma unroll
    for (int i = 0; i < 4; i++) {
#pragma unroll
        for (int j = 0; j < 4; j++) {
            int gcol = w * 64 + j * 16 + lm;
#pragma unroll
            for (int r = 0; r < 4; r++) {
                int grow = row0 + i * 16 + quad * 4 + r;
                if (grow < N_NODES)
                    Cb[(size_t)grow * HD + gcol] = f2bf(acc[i][j][r]);
            }
        }
    }

    // fused el/er: wave w == head w; 4-fma per lane + 16-lane shfl_xor reduce
    {
        float al[4], ar[4];
#pragma unroll
        for (int j = 0; j < 4; j++) {
            al[j] = attn_l[w * DH + j * 16 + lm];
            ar[j] = attn_r[w * DH + j * 16 + lm];
        }
#pragma unroll
        for (int i = 0; i < 4; i++) {
#pragma unroll
            for (int r = 0; r < 4; r++) {
                float sl = 0.f, sr = 0.f;
#pragma unroll
                for (int j = 0; j < 4; j++) {
                    sl += acc[i][j][r] * al[j];
                    sr += acc[i][j][r] * ar[j];
                }
#pragma unroll
                for (int off = 8; off > 0; off >>= 1) {
                    sl += __shfl_xor(sl, off);
                    sr += __shfl_xor(sr, off);
                }
                if (lm == 0) {
                    int grow = row0 + i * 16 + quad * 4 + r;
                    if (grow < N_NODES) {
                        el[(size_t)grow * NH + w] = sl;
                        er[(size_t)grow * NH + w] = sr;
                    }
                }
            }
        }
    }
}

// ---------------- 3-phase parallel exclusive scan of counts -------------------
__global__ __launch_bounds__(256) void partial_kernel(const int* __restrict__ counts,
                                                      int* __restrict__ bsums) {
    __shared__ int red[4];
    int i = blockIdx.x * 256 + threadIdx.x;
    int c = (i < N_NODES) ? counts[i] : 0;
#pragma unroll
    for (int off = 32; off > 0; off >>= 1) c += __shfl_down(c, off);
    if ((threadIdx.x & 63) == 0) red[threadIdx.x >> 6] = c;
    __syncthreads();
    if (threadIdx.x == 0) bsums[blockIdx.x] = red[0] + red[1] + red[2] + red[3];
}

__global__ __launch_bounds__(256) void bscan_kernel(const int* __restrict__ bsums,
                                                    int* __restrict__ boffs) {
    __shared__ int s[256];
    int tid = threadIdx.x;
    s[tid] = (tid < NB) ? bsums[tid] : 0;
    __syncthreads();
    for (int off = 1; off < 256; off <<= 1) {
        int x = s[tid];
        int a = (tid >= off) ? s[tid - off] : 0;
        __syncthreads();
        s[tid] = x + a;
        __syncthreads();
    }
    if (tid < NB) boffs[tid] = (tid > 0) ? s[tid - 1] : 0;
}

__global__ __launch_bounds__(256) void scatter_scan_kernel(const int* __restrict__ counts,
                                                           const int* __restrict__ boffs,
                                                           int* __restrict__ offsets,
                                                           int* __restrict__ cursor) {
    __shared__ int s[256];
    int tid = threadIdx.x;
    int i = blockIdx.x * 256 + tid;
    s[tid] = (i < N_NODES) ? counts[i] : 0;
    __syncthreads();
    for (int off = 1; off < 256; off <<= 1) {
        int x = s[tid];
        int a = (tid >= off) ? s[tid - off] : 0;
        __syncthreads();
        s[tid] = x + a;
        __syncthreads();
    }
    int excl = (tid > 0) ? s[tid - 1] : 0;
    int o = boffs[blockIdx.x] + excl;
    if (i < N_NODES) { offsets[i] = o; cursor[i] = o; }
    if (i == 0) offsets[N_NODES] = N_EDGES;
}

// ---------------- CSR placement only (scores computed on the fly in agg) ------
__global__ __launch_bounds__(256) void edge_place_kernel(const int* __restrict__ src,
                                                         const int* __restrict__ dst,
                                                         int* __restrict__ cursor,
                                                         int* __restrict__ srcs) {
    int e = blockIdx.x * blockDim.x + threadIdx.x;
    if (e >= N_EDGES) return;
    int u = src[e], v = dst[e];
    int pos = atomicAdd(&cursor[v], 1);
    srcs[pos] = u;
}

// ---------------- aggregation: one wave per dst, 8-edge software pipeline -----
// Edge weight computed on the fly: w = exp(lrelu(el[u][h] + er[v][h])).
// el is 800 KB (L2-resident); removes the w4s 12.8MB write+read round trip.
__device__ __forceinline__ float lrelu_exp(float x) {
    float y = fmaxf(x, NEG * x);
    return __expf(y);
}

__global__ __launch_bounds__(256) void agg_kernel(const unsigned short* __restrict__ ftb,
                                                  const float* __restrict__ el,
                                                  const float* __restrict__ er,
                                                  const int* __restrict__ srcs,
                                                  const int* __restrict__ offsets,
                                                  float* __restrict__ out) {
    int wv   = (blockIdx.x * blockDim.x + threadIdx.x) >> 6;  // node id
    int lane = threadIdx.x & 63;
    if (wv >= N_NODES) return;

    const int beg = offsets[wv];
    const int end = offsets[wv + 1];
    const int h   = lane >> 4;
    const size_t foff = (size_t)lane * 4;
    const float erv = er[(size_t)wv * NH + h];

    float4 acc = make_float4(0.f, 0.f, 0.f, 0.f);
    float dsum = 0.f;

    const int n8 = (end - beg) >> 3;   // full 8-edge blocks
    int u0, u1, u2, u3, u4, u5, u6, u7;
    if (n8 > 0) {
        const int* sp = srcs + beg;
        u0 = sp[0]; u1 = sp[1]; u2 = sp[2]; u3 = sp[3];
        u4 = sp[4]; u5 = sp[5]; u6 = sp[6]; u7 = sp[7];
        for (int b = 0; b < n8; b++) {
            const int base = beg + b * 8;
            // preload next block's indices (breaks the idx->gather chain)
            int v0 = 0, v1 = 0, v2 = 0, v3 = 0, v4 = 0, v5 = 0, v6 = 0, v7 = 0;
            if (b + 1 < n8) {
                const int* np = srcs + base + 8;
                v0 = np[0]; v1 = np[1]; v2 = np[2]; v3 = np[3];
                v4 = np[4]; v5 = np[5]; v6 = np[6]; v7 = np[7];
            }
            // 8 independent 512B gathers + 8 tiny L2-hot el gathers in flight
            ushort4 f0 = *(const ushort4*)(ftb + (size_t)u0 * HD + foff);
            ushort4 f1 = *(const ushort4*)(ftb + (size_t)u1 * HD + foff);
            ushort4 f2 = *(const ushort4*)(ftb + (size_t)u2 * HD + foff);
            ushort4 f3 = *(const ushort4*)(ftb + (size_t)u3 * HD + foff);
            ushort4 f4 = *(const ushort4*)(ftb + (size_t)u4 * HD + foff);
            ushort4 f5 = *(const ushort4*)(ftb + (size_t)u5 * HD + foff);
            ushort4 f6 = *(const ushort4*)(ftb + (size_t)u6 * HD + foff);
            ushort4 f7 = *(const ushort4*)(ftb + (size_t)u7 * HD + foff);
            float e0 = el[(size_t)u0 * NH + h];
            float e1 = el[(size_t)u1 * NH + h];
            float e2 = el[(size_t)u2 * NH + h];
            float e3 = el[(size_t)u3 * NH + h];
            float e4 = el[(size_t)u4 * NH + h];
            float e5 = el[(size_t)u5 * NH + h];
            float e6 = el[(size_t)u6 * NH + h];
            float e7 = el[(size_t)u7 * NH + h];
            float w0 = lrelu_exp(e0 + erv), w1 = lrelu_exp(e1 + erv);
            float w2 = lrelu_exp(e2 + erv), w3 = lrelu_exp(e3 + erv);
            float w4 = lrelu_exp(e4 + erv), w5 = lrelu_exp(e5 + erv);
            float w6 = lrelu_exp(e6 + erv), w7 = lrelu_exp(e7 + erv);
            acc.x += w0 * bf2f(f0.x) + w1 * bf2f(f1.x) + w2 * bf2f(f2.x) + w3 * bf2f(f3.x)
                   + w4 * bf2f(f4.x) + w5 * bf2f(f5.x) + w6 * bf2f(f6.x) + w7 * bf2f(f7.x);
            acc.y += w0 * bf2f(f0.y) + w1 * bf2f(f1.y) + w2 * bf2f(f2.y) + w3 * bf2f(f3.y)
                   + w4 * bf2f(f4.y) + w5 * bf2f(f5.y) + w6 * bf2f(f6.y) + w7 * bf2f(f7.y);
            acc.z += w0 * bf2f(f0.z) + w1 * bf2f(f1.z) + w2 * bf2f(f2.z) + w3 * bf2f(f3.z)
                   + w4 * bf2f(f4.z) + w5 * bf2f(f5.z) + w6 * bf2f(f6.z) + w7 * bf2f(f7.z);
            acc.w += w0 * bf2f(f0.w) + w1 * bf2f(f1.w) + w2 * bf2f(f2.w) + w3 * bf2f(f3.w)
                   + w4 * bf2f(f4.w) + w5 * bf2f(f5.w) + w6 * bf2f(f6.w) + w7 * bf2f(f7.w);
            dsum += ((w0 + w1) + (w2 + w3)) + ((w4 + w5) + (w6 + w7));
            u0 = v0; u1 = v1; u2 = v2; u3 = v3;
            u4 = v4; u5 = v5; u6 = v6; u7 = v7;
        }
    }
    // predicated-parallel tail (1..7 edges): duplicate-load sp[0], zero weights
    {
        const int p0  = beg + n8 * 8;
        const int rem = end - p0;
        if (rem > 0) {
            const int* sp = srcs + p0;
            int x0 = sp[0];
            int x1 = (1 < rem) ? sp[1] : x0;
            int x2 = (2 < rem) ? sp[2] : x0;
            int x3 = (3 < rem) ? sp[3] : x0;
            int x4 = (4 < rem) ? sp[4] : x0;
            int x5 = (5 < rem) ? sp[5] : x0;
            int x6 = (6 < rem) ? sp[6] : x0;
            ushort4 f0 = *(const ushort4*)(ftb + (size_t)x0 * HD + foff);
            ushort4 f1 = *(const ushort4*)(ftb + (size_t)x1 * HD + foff);
            ushort4 f2 = *(const ushort4*)(ftb + (size_t)x2 * HD + foff);
            ushort4 f3 = *(const ushort4*)(ftb + (size_t)x3 * HD + foff);
            ushort4 f4 = *(const ushort4*)(ftb + (size_t)x4 * HD + foff);
            ushort4 f5 = *(const ushort4*)(ftb + (size_t)x5 * HD + foff);
            ushort4 f6 = *(const ushort4*)(ftb + (size_t)x6 * HD + foff);
            float e0 = el[(size_t)x0 * NH + h];
            float e1 = el[(size_t)x1 * NH + h];
            float e2 = el[(size_t)x2 * NH + h];
            float e3 = el[(size_t)x3 * NH + h];
            float e4 = el[(size_t)x4 * NH + h];
            float e5 = el[(size_t)x5 * NH + h];
            float e6 = el[(size_t)x6 * NH + h];
            float w0 = lrelu_exp(e0 + erv);
            float w1 = (1 < rem) ? lrelu_exp(e1 + erv) : 0.f;
            float w2 = (2 < rem) ? lrelu_exp(e2 + erv) : 0.f;
            float w3 = (3 < rem) ? lrelu_exp(e3 + erv) : 0.f;
            float w4 = (4 < rem) ? lrelu_exp(e4 + erv) : 0.f;
            float w5 = (5 < rem) ? lrelu_exp(e5 + erv) : 0.f;
            float w6 = (6 < rem) ? lrelu_exp(e6 + erv) : 0.f;
            acc.x += w0 * bf2f(f0.x) + w1 * bf2f(f1.x) + w2 * bf2f(f2.x) + w3 * bf2f(f3.x)
                   + w4 * bf2f(f4.x) + w5 * bf2f(f5.x) + w6 * bf2f(f6.x);
            acc.y += w0 * bf2f(f0.y) + w1 * bf2f(f1.y) + w2 * bf2f(f2.y) + w3 * bf2f(f3.y)
                   + w4 * bf2f(f4.y) + w5 * bf2f(f5.y) + w6 * bf2f(f6.y);
            acc.z += w0 * bf2f(f0.z) + w1 * bf2f(f1.z) + w2 * bf2f(f2.z) + w3 * bf2f(f3.z)
                   + w4 * bf2f(f4.z) + w5 * bf2f(f5.z) + w6 * bf2f(f6.z);
            acc.w += w0 * bf2f(f0.w) + w1 * bf2f(f1.w) + w2 * bf2f(f2.w) + w3 * bf2f(f3.w)
                   + w4 * bf2f(f4.w) + w5 * bf2f(f5.w) + w6 * bf2f(f6.w);
            dsum += ((w0 + w1) + (w2 + w3)) + ((w4 + w5) + w6);
        }
    }

    float inv = (dsum > 0.f) ? (1.f / dsum) : 0.f;
    acc.x *= inv; acc.y *= inv; acc.z *= inv; acc.w *= inv;
    *(float4*)(out + (size_t)wv * HD + foff) = acc;
}

// ---------------- launch ----------------
extern "C" void kernel_launch(void* const* d_in, const int* in_sizes, int n_in,
                              void* d_out, int out_size, void* d_ws, size_t ws_size,
                              hipStream_t stream) {
    const float* feat   = (const float*)d_in[0];
    const float* W      = (const float*)d_in[1];
    const float* attn_l = (const float*)d_in[2];
    const float* attn_r = (const float*)d_in[3];
    const int*   src    = (const int*)d_in[4];
    const int*   dst    = (const int*)d_in[5];
    float* out = (float*)d_out;

    char* p = (char*)d_ws;
    auto alloc = [&](size_t bytes) -> char* {
        char* r = p;
        p += (bytes + 255) & ~(size_t)255;
        return r;
    };
    unsigned short* ftb     = (unsigned short*)alloc((size_t)N_NODES * HD * 2); // 25.6 MB
    unsigned short* WtbT    = (unsigned short*)alloc((size_t)IN_F * HD * 2);
    float*          el      = (float*)alloc((size_t)N_NODES * NH * 4);
    float*          er      = (float*)alloc((size_t)N_NODES * NH * 4);
    int*            srcs    = (int*)alloc((size_t)N_EDGES * 4);          // 3.2 MB
    int*            counts  = (int*)alloc((size_t)N_NODES * 4);
    int*            offsets = (int*)alloc((size_t)(N_NODES + 1) * 4);
    int*            cursor  = (int*)alloc((size_t)N_NODES * 4);
    int*            bsums   = (int*)alloc((size_t)NB * 4);
    int*            boffs   = (int*)alloc((size_t)NB * 4);

    // 1. setup: zero counts + W -> WtbT tiled/swizzled bf16 (one launch)
    setup_kernel<<<NB + (IN_F * HD + 255) / 256, 256, 0, stream>>>(W, WtbT, counts);
    // 2. per-dst counts
    count_kernel<<<(N_EDGES + 255) / 256, 256, 0, stream>>>(dst, counts);
    // 3. ftb = bf16(feat @ W) + fused el/er (global_load_lds B, dbuf)
    gemm_kernel<<<(N_NODES + 63) / 64, 256, 0, stream>>>(feat, WtbT, attn_l, attn_r,
                                                         ftb, el, er);
    // 4. parallel 3-phase scan -> offsets, cursor
    partial_kernel<<<NB, 256, 0, stream>>>(counts, bsums);
    bscan_kernel<<<1, 256, 0, stream>>>(bsums, boffs);
    scatter_scan_kernel<<<NB, 256, 0, stream>>>(counts, boffs, offsets, cursor);
    // 5. CSR placement
    edge_place_kernel<<<(N_EDGES + 255) / 256, 256, 0, stream>>>(src, dst, cursor, srcs);
    // 6. aggregate per destination node (scores + normalization fused)
    agg_kernel<<<(N_NODES + 3) / 4, 256, 0, stream>>>(ftb, el, er, srcs, offsets, out);
}